// Round 15
// baseline (435.514 us; speedup 1.0000x reference)
//
#include <hip/hip_runtime.h>
#include <hip/hip_bf16.h>

// AutoInt+MLP fused forward, MI355X gfx950.  Round 15:
//  - attn: round-13 verbatim (~270us; plateaued at 3 blocks/CU, dependency-bound).
//  - dnn : round-10 shape (256 thr, M=32, C1[2][8]) + PAIRED-FIELD K-loop:
//          2 fields per iteration -> 20 barriers (was 39), 64 MFMA + 16KB of
//          contiguous B-loads per latency window (was 32 + 8KB).
//          r14's 512-thr variant regressed (wave count wasn't the limiter).
//  HARD RULES: no 2-arg __launch_bounds__ (r5/8/9 corrupt, r6 spill); no
//  heterogeneous-role merged dispatch (r11); dnn M=64 spills (r6/r12).

#define NF     39
#define EMB    64
#define NLAYER 3
#define VOCAB  1000
#define FLAT   2496
#define H1     512
#define H2     256

typedef __attribute__((ext_vector_type(8))) short  short8;
typedef __attribute__((ext_vector_type(4))) float  floatx4;

__device__ __forceinline__ short8 ld8s(const unsigned short* p) {
    return *(const short8*)p;
}
__device__ __forceinline__ float b2f(unsigned short h) {
    union { unsigned u; float f; } x; x.u = ((unsigned)h) << 16; return x.f;
}
__device__ __forceinline__ unsigned short f2b(float f) {
    union { float f; unsigned u; } x; x.f = f;
    unsigned u = x.u;
    return (unsigned short)((u + 0x7fffu + ((u >> 16) & 1u)) >> 16);
}
// 2 floats -> packed bf16x2 in ONE VALU op (gfx950 hw cvt, RNE)
__device__ __forceinline__ unsigned cvt_pk(float a, float b) {
#if defined(__gfx950__)
    unsigned r;
    asm("v_cvt_pk_bf16_f32 %0, %1, %2" : "=v"(r) : "v"(a), "v"(b));
    return r;
#else
    return (unsigned)f2b(a) | ((unsigned)f2b(b) << 16);
#endif
}

// ------- prep: attention weights f32 [L][64(k)][64(o)] -> bf16 [L][o][k] --------------
__global__ void attw_t(const float* __restrict__ WQ, const float* __restrict__ WK,
                       const float* __restrict__ WV, const float* __restrict__ WR,
                       unsigned short* __restrict__ wqt, unsigned short* __restrict__ wkt,
                       unsigned short* __restrict__ wvt, unsigned short* __restrict__ wrt)
{
    int idx = blockIdx.x * 256 + threadIdx.x;       // 4*3*4096 = 49152
    if (idx >= 4 * 3 * 4096) return;
    int mat = idx / 12288;
    int rem = idx % 12288;
    int l   = rem / 4096;
    int ok  = rem % 4096;
    int o = ok >> 6, k = ok & 63;
    const float*    src = (mat == 0) ? WQ : (mat == 1) ? WK : (mat == 2) ? WV : WR;
    unsigned short* dst = (mat == 0) ? wqt : (mat == 1) ? wkt : (mat == 2) ? wvt : wrt;
    dst[l * 4096 + o * 64 + k] = f2b(src[l * 4096 + k * 64 + o]);
}

// ------- prep: W1 f32 [2496][512] -> bf16 fragment-linear w1p --------------------------
__global__ void w1pack(const float* __restrict__ W1, unsigned short* __restrict__ w1p)
{
    int t = blockIdx.x * 256 + threadIdx.x;        // 624*256 = 159744 = 2496*64
    int lane = t & 63, grp = t >> 6;               // grp 0..2495
    int ot = grp / 78, kk = grp % 78;
    int q = lane >> 4, n = ot * 16 + (lane & 15);
    int kb = kk * 32 + q * 8;
    unsigned short* dst = w1p + grp * 512 + lane * 8;
    #pragma unroll
    for (int j = 0; j < 8; ++j)
        dst[j] = f2b(W1[(kb + j) * 512 + n]);
}

// ------- prep: W2 f32 [512][256] -> bf16 fragment-linear w2p ---------------------------
__global__ void w2pack(const float* __restrict__ W2, unsigned short* __restrict__ w2p)
{
    int t = blockIdx.x * 256 + threadIdx.x;        // 64*256 = 16384 = 256*64
    int lane = t & 63, grp = t >> 6;               // grp 0..255
    int ot = grp / 16, kk = grp % 16;
    int q = lane >> 4, n = ot * 16 + (lane & 15);
    int kb = kk * 32 + q * 8;
    unsigned short* dst = w2p + grp * 512 + lane * 8;
    #pragma unroll
    for (int j = 0; j < 8; ++j)
        dst[j] = f2b(W2[(kb + j) * 256 + n]);
}

// ------- fused attention (ROUND-13 VERBATIM) ------------------------------------------
// block = 256 thr (4 waves), 2 samples/block; wave = (sample, head).
// LDS: xs 13824 + arena 4x9472 + red 16 = 51728 B  -> 3 blocks/CU (LDS-limited).
__global__ void __launch_bounds__(256) attn_kernel(
    const int* __restrict__ X,
    const float* __restrict__ embf,
    const unsigned short* __restrict__ wqt,
    const unsigned short* __restrict__ wkt,
    const unsigned short* __restrict__ wvt,
    const unsigned short* __restrict__ wrt,
    const float* __restrict__ wlinf,
    float* __restrict__ att_out)
{
    __shared__ unsigned short xs[2][48 * 72];      // [sample][token 48][col 64+8pad]
    __shared__ unsigned short arena[4][4736];
    __shared__ float red[4];

    const int tid  = threadIdx.x;
    const int wid  = tid >> 6;
    const int lane = tid & 63;
    const int sl   = wid >> 1;          // sample-in-block
    const int h    = wid & 1;           // head
    const int quad = lane >> 4;
    const int l16  = lane & 15;
    const int samp = blockIdx.x * 2 + sl;

    unsigned short* xss = xs[sl];
    unsigned short* qs  = arena[wid];
    unsigned short* ks  = qs + 1920;
    unsigned short* Ps  = qs;           // alias (qs/ks dead after S^T)
    unsigned short* vt  = qs + 3456;    // 32 x 40 (toks of one K-half)

    // ---- embedding gather: wave fills its sample's cols h*32..h*32+31 -----------------
    {
        const int tq = lane >> 4;            // 0..3
        const int cp = (lane & 15) * 2;      // 0,2,..,30
        const int col = h * 32 + cp;
        const int* xrow = X + samp * NF;
        #pragma unroll
        for (int t0 = 0; t0 < 48; t0 += 4) {
            int t = t0 + tq;
            unsigned pk = 0;
            if (t < NF) {
                int row = xrow[t] + t * VOCAB;
                const float2 v = *(const float2*)&embf[row * EMB + col];
                pk = cvt_pk(v.x, v.y);
            }
            *(unsigned*)&xss[t * 72 + col] = pk;   // rows 39..47 zeroed
        }
    }
    __syncthreads();

    for (int layer = 0; layer < NLAYER; ++layer) {
        const unsigned short* wq  = wqt + layer * 4096;
        const unsigned short* wk  = wkt + layer * 4096;
        const unsigned short* wvp = wvt + layer * 4096;
        const unsigned short* wr  = wrt + layer * 4096;

        // ---- Q,K projections, transposed orientation: C = W^T @ x^T -------------------
        #pragma unroll
        for (int mat = 0; mat < 2; ++mat) {
            const unsigned short* wt = mat ? wk : wq;
            unsigned short* dst = mat ? ks : qs;
            #pragma unroll
            for (int ot = 0; ot < 2; ++ot) {
                #pragma unroll
                for (int tt = 0; tt < 3; ++tt) {
                    floatx4 c = {0.f, 0.f, 0.f, 0.f};
                    #pragma unroll
                    for (int kk = 0; kk < 2; ++kk) {
                        short8 a = ld8s(&wt[(h * 32 + ot * 16 + l16) * 64 + kk * 32 + quad * 8]);
                        short8 b = ld8s(&xss[(tt * 16 + l16) * 72 + kk * 32 + quad * 8]);
                        c = __builtin_amdgcn_mfma_f32_16x16x32_bf16(a, b, c, 0, 0, 0);
                    }
                    uint2 w;
                    w.x = cvt_pk(c[0], c[1]);
                    w.y = cvt_pk(c[2], c[3]);
                    *(uint2*)&dst[(tt * 16 + l16) * 40 + ot * 16 + quad * 4] = w;
                }
            }
        }

        // ---- S^T = K @ Q^T  (C row = j, col = i) --------------------------------------
        floatx4 ST[3][3];
        #pragma unroll
        for (int jt = 0; jt < 3; ++jt) {
            short8 a = ld8s(&ks[(jt * 16 + l16) * 40 + quad * 8]);
            #pragma unroll
            for (int it = 0; it < 3; ++it) {
                short8 b = ld8s(&qs[(it * 16 + l16) * 40 + quad * 8]);
                floatx4 z = {0.f, 0.f, 0.f, 0.f};
                ST[jt][it] = __builtin_amdgcn_mfma_f32_16x16x32_bf16(a, b, z, 0, 0, 0);
            }
        }

        // ---- softmax over j (local + shfl_xor 16,32); write P in [i][j] to Ps ---------
        #pragma unroll
        for (int it = 0; it < 3; ++it) {
            float p[3][4];
            float sum = 0.f;
            #pragma unroll
            for (int jt = 0; jt < 3; ++jt)
                #pragma unroll
                for (int r = 0; r < 4; ++r) {
                    int j = jt * 16 + quad * 4 + r;
                    float e = (j < NF) ? __expf(ST[jt][it][r]) : 0.f;
                    p[jt][r] = e;
                    sum += e;
                }
            sum += __shfl_xor(sum, 16, 64);
            sum += __shfl_xor(sum, 32, 64);
            float inv = 1.0f / sum;
            #pragma unroll
            for (int jt = 0; jt < 3; ++jt) {
                uint2 w;
                w.x = cvt_pk(p[jt][0] * inv, p[jt][1] * inv);
                w.y = cvt_pk(p[jt][2] * inv, p[jt][3] * inv);
                *(uint2*)&Ps[(it * 16 + l16) * 72 + jt * 16 + quad * 4] = w;
            }
            uint2 z2; z2.x = 0; z2.y = 0;                 // zero K-pad cols 48..63
            *(uint2*)&Ps[(it * 16 + l16) * 72 + 48 + quad * 4] = z2;
        }

        // ---- V projection: mt=0,1 -> vT (toks 0..31); mt=2 held in regs ---------------
        unsigned sv[2][2];      // [nt][lo/hi] packed mt=2 C-frag (toks 32..47)
        #pragma unroll
        for (int mt = 0; mt < 3; ++mt) {
            #pragma unroll
            for (int nt = 0; nt < 2; ++nt) {
                floatx4 c = {0.f, 0.f, 0.f, 0.f};
                #pragma unroll
                for (int kk = 0; kk < 2; ++kk) {
                    short8 a = ld8s(&xss[(mt * 16 + l16) * 72 + kk * 32 + quad * 8]);
                    short8 b = ld8s(&wvp[(h * 32 + nt * 16 + l16) * 64 + kk * 32 + quad * 8]);
                    c = __builtin_amdgcn_mfma_f32_16x16x32_bf16(a, b, c, 0, 0, 0);
                }
                unsigned lo = cvt_pk(c[0], c[1]);
                unsigned hi = cvt_pk(c[2], c[3]);
                if (mt < 2) {
                    uint2 w; w.x = lo; w.y = hi;      // vT[d][tok_local mt*16+quad*4 ..+3]
                    *(uint2*)&vt[(nt * 16 + l16) * 40 + mt * 16 + quad * 4] = w;
                } else {
                    sv[nt][0] = lo; sv[nt][1] = hi;
                }
            }
        }

        // ---- R projection, transposed: O^T init (row = d, col = tok) ------------------
        floatx4 O[2][3];        // [dt][it]
        #pragma unroll
        for (int dt = 0; dt < 2; ++dt) {
            #pragma unroll
            for (int it = 0; it < 3; ++it) {
                floatx4 c = {0.f, 0.f, 0.f, 0.f};
                #pragma unroll
                for (int kk = 0; kk < 2; ++kk) {
                    short8 a = ld8s(&wr[(h * 32 + dt * 16 + l16) * 64 + kk * 32 + quad * 8]);
                    short8 b = ld8s(&xss[(it * 16 + l16) * 72 + kk * 32 + quad * 8]);
                    c = __builtin_amdgcn_mfma_f32_16x16x32_bf16(a, b, c, 0, 0, 0);
                }
                O[dt][it] = c;
            }
        }

        __syncthreads();   // all waves done reading xs

        // ---- O^T += V^T @ P^T, kk=0 (toks 0..31): A = vt, B = Ps ----------------------
        {
            short8 b0 = ld8s(&Ps[(l16) * 72 + quad * 8]);
            short8 b1 = ld8s(&Ps[(16 + l16) * 72 + quad * 8]);
            short8 b2 = ld8s(&Ps[(32 + l16) * 72 + quad * 8]);
            #pragma unroll
            for (int dt = 0; dt < 2; ++dt) {
                short8 a = ld8s(&vt[(dt * 16 + l16) * 40 + quad * 8]);
                O[dt][0] = __builtin_amdgcn_mfma_f32_16x16x32_bf16(a, b0, O[dt][0], 0, 0, 0);
                O[dt][1] = __builtin_amdgcn_mfma_f32_16x16x32_bf16(a, b1, O[dt][1], 0, 0, 0);
                O[dt][2] = __builtin_amdgcn_mfma_f32_16x16x32_bf16(a, b2, O[dt][2], 0, 0, 0);
            }
        }
        // ---- refill vT with toks 32..63 (local 0..15 = sv, 16..31 = zeros) ------------
        #pragma unroll
        for (int nt = 0; nt < 2; ++nt) {
            uint2 w; w.x = sv[nt][0]; w.y = sv[nt][1];
            *(uint2*)&vt[(nt * 16 + l16) * 40 + quad * 4] = w;
            uint2 z; z.x = 0; z.y = 0;
            *(uint2*)&vt[(nt * 16 + l16) * 40 + 16 + quad * 4] = z;
        }
        // ---- O^T += V^T @ P^T, kk=1 (toks 32..63) -------------------------------------
        {
            short8 b0 = ld8s(&Ps[(l16) * 72 + 32 + quad * 8]);
            short8 b1 = ld8s(&Ps[(16 + l16) * 72 + 32 + quad * 8]);
            short8 b2 = ld8s(&Ps[(32 + l16) * 72 + 32 + quad * 8]);
            #pragma unroll
            for (int dt = 0; dt < 2; ++dt) {
                short8 a = ld8s(&vt[(dt * 16 + l16) * 40 + quad * 8]);
                O[dt][0] = __builtin_amdgcn_mfma_f32_16x16x32_bf16(a, b0, O[dt][0], 0, 0, 0);
                O[dt][1] = __builtin_amdgcn_mfma_f32_16x16x32_bf16(a, b1, O[dt][1], 0, 0, 0);
                O[dt][2] = __builtin_amdgcn_mfma_f32_16x16x32_bf16(a, b2, O[dt][2], 0, 0, 0);
            }
        }

        // ---- next x = relu(O^T): write xss[tok][d] with b64 of 4 consecutive d --------
        #pragma unroll
        for (int dt = 0; dt < 2; ++dt)
            #pragma unroll
            for (int it = 0; it < 3; ++it) {
                uint2 w;
                w.x = cvt_pk(fmaxf(O[dt][it][0], 0.f), fmaxf(O[dt][it][1], 0.f));
                w.y = cvt_pk(fmaxf(O[dt][it][2], 0.f), fmaxf(O[dt][it][3], 0.f));
                *(uint2*)&xss[(it * 16 + l16) * 72 + h * 32 + dt * 16 + quad * 4] = w;
            }

        __syncthreads();
    }

    // ---- att logit: relu( att_flat . Wlin ) -------------------------------------------
    {
        float acc = 0.f;
        const int c = lane & 31, tp = lane >> 5;
        const int col = h * 32 + c;
        for (int t0 = 0; t0 < 40; t0 += 2) {
            int t = t0 + tp;
            if (t < NF)
                acc += b2f(xss[t * 72 + col]) * wlinf[t * EMB + col];
        }
        #pragma unroll
        for (int off = 1; off < 64; off <<= 1)
            acc += __shfl_xor(acc, off, 64);
        if (lane == 0) red[wid] = acc;
        __syncthreads();
        if (tid < 2) {
            float v2 = red[tid * 2] + red[tid * 2 + 1];
            att_out[blockIdx.x * 2 + tid] = fmaxf(v2, 0.f);
        }
    }
}

// ------- DNN: 32-sample tile, 256 thr, PAIRED-FIELD K-loop ----------------------------
// 512 blocks x 256 thr. C1[2][8] (register-safe). 20 barriers (2 fields/iter);
// 64 MFMA + 16KB contiguous B-loads per window. LDS: ea 18432 + h1s 33280 = 51712 B.
__global__ void __launch_bounds__(256) dnn_kernel(
    const int* __restrict__ X,
    const float* __restrict__ embf,
    const unsigned short* __restrict__ w1p,
    const float* __restrict__ b1v,
    const unsigned short* __restrict__ w2p,
    const float* __restrict__ b2v,
    const float* __restrict__ w3v,
    const float* __restrict__ b3v,
    const float* __restrict__ att_in,
    float* __restrict__ out)
{
    __shared__ unsigned short ea[2][2][32 * 72];  // [buf][field-in-pair][samp 32][64+8pad]
    __shared__ unsigned short h1s[32 * 520];      // h1 [32][512+8pad]; h2 [32][264] aliases
    unsigned short* h2s = h1s;

    const int tid  = threadIdx.x;
    const int wid  = tid >> 6, lane = tid & 63, quad = lane >> 4, l16 = lane & 15;
    const int S0   = blockIdx.x * 32;

    floatx4 C1[2][8];
    #pragma unroll
    for (int mt = 0; mt < 2; ++mt)
        #pragma unroll
        for (int nt = 0; nt < 8; ++nt)
            C1[mt][nt] = (floatx4){0.f, 0.f, 0.f, 0.f};

    const int gs = tid >> 3;        // 0..31 sample for staging
    const int gg = tid & 7;         // 8 floats each

    // prologue: stage pair 0 (fields 0,1) into buf 0
    #pragma unroll
    for (int g = 0; g < 2; ++g) {
        int row = X[(S0 + gs) * NF + g] + g * VOCAB;
        const float4* src = (const float4*)&embf[row * EMB + gg * 8];
        float4 v0 = src[0], v1 = src[1];
        uint4 u;
        u.x = cvt_pk(v0.x, v0.y); u.y = cvt_pk(v0.z, v0.w);
        u.z = cvt_pk(v1.x, v1.y); u.w = cvt_pk(v1.z, v1.w);
        *(uint4*)&ea[0][g][gs * 72 + gg * 8] = u;
    }
    __syncthreads();

    // ---- phase 1: h1 = emb(32 x 2496) @ W1, 2 fields per iteration, 20 barriers -------
    for (int p = 0; p < 20; ++p) {
        const int f0 = 2 * p, f1 = f0 + 1;
        // stage pair p+1 into the other buffer (guarded; uniform branches)
        if (f0 + 2 < NF) {
            int row = X[(S0 + gs) * NF + f0 + 2] + (f0 + 2) * VOCAB;
            const float4* src = (const float4*)&embf[row * EMB + gg * 8];
            float4 v0 = src[0], v1 = src[1];
            uint4 u;
            u.x = cvt_pk(v0.x, v0.y); u.y = cvt_pk(v0.z, v0.w);
            u.z = cvt_pk(v1.x, v1.y); u.w = cvt_pk(v1.z, v1.w);
            *(uint4*)&ea[(p + 1) & 1][0][gs * 72 + gg * 8] = u;
        }
        if (f0 + 3 < NF) {
            int row = X[(S0 + gs) * NF + f0 + 3] + (f0 + 3) * VOCAB;
            const float4* src = (const float4*)&embf[row * EMB + gg * 8];
            float4 v0 = src[0], v1 = src[1];
            uint4 u;
            u.x = cvt_pk(v0.x, v0.y); u.y = cvt_pk(v0.z, v0.w);
            u.z = cvt_pk(v1.x, v1.y); u.w = cvt_pk(v1.z, v1.w);
            *(uint4*)&ea[(p + 1) & 1][1][gs * 72 + gg * 8] = u;
        }

        const unsigned short* e0 = ea[p & 1][0];
        const unsigned short* e1 = ea[p & 1][1];
        short8 a0[2][2], a1[2][2];
        #pragma unroll
        for (int mt = 0; mt < 2; ++mt) {
            a0[mt][0] = ld8s(&e0[(mt * 16 + l16) * 72 + quad * 8]);
            a0[mt][1] = ld8s(&e0[(mt * 16 + l16) * 72 + 32 + quad * 8]);
        }
        const bool has_f1 = (f1 < NF);
        if (has_f1) {
            #pragma unroll
            for (int mt = 0; mt < 2; ++mt) {
                a1[mt][0] = ld8s(&e1[(mt * 16 + l16) * 72 + quad * 8]);
                a1[mt][1] = ld8s(&e1[(mt * 16 + l16) * 72 + 32 + quad * 8]);
            }
        }
        #pragma unroll
        for (int nt = 0; nt < 8; ++nt) {
            // 4 contiguous 1KB segments: kchunks f0*2 .. f0*2+3
            const unsigned short* bp = w1p + (((wid * 8 + nt) * 78 + f0 * 2) * 64 + lane) * 8;
            short8 b00 = ld8s(bp);
            short8 b01 = ld8s(bp + 512);
            #pragma unroll
            for (int mt = 0; mt < 2; ++mt) {
                C1[mt][nt] = __builtin_amdgcn_mfma_f32_16x16x32_bf16(a0[mt][0], b00, C1[mt][nt], 0, 0, 0);
                C1[mt][nt] = __builtin_amdgcn_mfma_f32_16x16x32_bf16(a0[mt][1], b01, C1[mt][nt], 0, 0, 0);
            }
            if (has_f1) {
                short8 b10 = ld8s(bp + 1024);
                short8 b11 = ld8s(bp + 1536);
                #pragma unroll
                for (int mt = 0; mt < 2; ++mt) {
                    C1[mt][nt] = __builtin_amdgcn_mfma_f32_16x16x32_bf16(a1[mt][0], b10, C1[mt][nt], 0, 0, 0);
                    C1[mt][nt] = __builtin_amdgcn_mfma_f32_16x16x32_bf16(a1[mt][1], b11, C1[mt][nt], 0, 0, 0);
                }
            }
        }
        __syncthreads();   // protects both ea buffers (waves drift <= 1 iter)
    }

    // bias + relu, write ALL of h1 to LDS (each wave owns 128 cols)
    #pragma unroll
    for (int nt = 0; nt < 8; ++nt) {
        float bb = b1v[wid * 128 + nt * 16 + l16];
        #pragma unroll
        for (int mt = 0; mt < 2; ++mt) {
            #pragma unroll
            for (int r = 0; r < 4; ++r) {
                float v = fmaxf(C1[mt][nt][r] + bb, 0.f);
                h1s[(mt * 16 + quad * 4 + r) * 520 + wid * 128 + nt * 16 + l16] = f2b(v);
            }
        }
    }
    __syncthreads();

    // ---- phase 2: h2 = h1(32 x 512) @ W2, single pass, wave owns 64 N-cols ------------
    floatx4 C2[2][4];
    #pragma unroll
    for (int mt = 0; mt < 2; ++mt)
        #pragma unroll
        for (int nt = 0; nt < 4; ++nt)
            C2[mt][nt] = (floatx4){0.f, 0.f, 0.f, 0.f};

    #pragma unroll 4
    for (int kk = 0; kk < 16; ++kk) {
        short8 a0 = ld8s(&h1s[(l16) * 520 + kk * 32 + quad * 8]);
        short8 a1 = ld8s(&h1s[(16 + l16) * 520 + kk * 32 + quad * 8]);
        #pragma unroll
        for (int nt = 0; nt < 4; ++nt) {
            short8 b = ld8s(w2p + (((wid * 4 + nt) * 16 + kk) * 64 + lane) * 8);
            C2[0][nt] = __builtin_amdgcn_mfma_f32_16x16x32_bf16(a0, b, C2[0][nt], 0, 0, 0);
            C2[1][nt] = __builtin_amdgcn_mfma_f32_16x16x32_bf16(a1, b, C2[1][nt], 0, 0, 0);
        }
    }
    __syncthreads();    // h1 reads complete -> safe to alias h2s onto h1s

    #pragma unroll
    for (int nt = 0; nt < 4; ++nt) {
        float bb = b2v[wid * 64 + nt * 16 + l16];
        #pragma unroll
        for (int mt = 0; mt < 2; ++mt)
            #pragma unroll
            for (int r = 0; r < 4; ++r)
                h2s[(mt * 16 + quad * 4 + r) * 264 + wid * 64 + nt * 16 + l16] =
                    f2b(fmaxf(C2[mt][nt][r] + bb, 0.f));
    }
    __syncthreads();

    // ---- phase 3: dnn = relu(h2 . W3 + b3); out = sigmoid(att + dnn), f32 -------------
    {
        int s = tid >> 3, part = tid & 7;     // 8 lanes per sample, 32 elems each
        float acc = 0.f;
        #pragma unroll 8
        for (int j = 0; j < 32; ++j) {
            int jj = part * 32 + j;
            acc += b2f(h2s[s * 264 + jj]) * w3v[jj];
        }
        acc += __shfl_xor(acc, 1, 64);
        acc += __shfl_xor(acc, 2, 64);
        acc += __shfl_xor(acc, 4, 64);
        if (part == 0) {
            float dnn = fmaxf(acc + b3v[0], 0.f);
            float v = dnn + att_in[S0 + s];
            out[S0 + s] = 1.f / (1.f + __expf(-v));
        }
    }
}

extern "C" void kernel_launch(void* const* d_in, const int* in_sizes, int n_in,
                              void* d_out, int out_size, void* d_ws, size_t ws_size,
                              hipStream_t stream)
{
    (void)in_sizes; (void)n_in; (void)out_size; (void)ws_size;

    const int*   X    = (const int*)d_in[0];
    const float* emb  = (const float*)d_in[1];
    const float* WQ   = (const float*)d_in[2];
    const float* WK   = (const float*)d_in[3];
    const float* WV   = (const float*)d_in[4];
    const float* WR   = (const float*)d_in[5];
    const float* W1   = (const float*)d_in[6];
    const float* b1   = (const float*)d_in[7];
    const float* W2   = (const float*)d_in[8];
    const float* b2   = (const float*)d_in[9];
    const float* W3   = (const float*)d_in[10];
    const float* b3   = (const float*)d_in[11];
    const float* Wlin = (const float*)d_in[12];

    char* ws = (char*)d_ws;
    float*          att_logit = (float*)ws;                          // 16384 f32 = 64KB
    unsigned short* wqt = (unsigned short*)(ws + 65536);             // 3*4096 shorts each
    unsigned short* wkt = wqt + 3 * 4096;
    unsigned short* wvt = wkt + 3 * 4096;
    unsigned short* wrt = wvt + 3 * 4096;
    unsigned short* w1p = wrt + 3 * 4096;                            // 2496*512 shorts
    unsigned short* w2p = w1p + 2496 * 512;                          // 256*512 shorts

    attw_t<<<192, 256, 0, stream>>>(WQ, WK, WV, WR, wqt, wkt, wvt, wrt);
    w1pack<<<624, 256, 0, stream>>>(W1, w1p);
    w2pack<<<64, 256, 0, stream>>>(W2, w2p);
    attn_kernel<<<8192, 256, 0, stream>>>(X, emb, wqt, wkt, wvt, wrt, Wlin, att_logit);
    dnn_kernel<<<512, 256, 0, stream>>>(X, emb, w1p, b1, w2p, b2, W3, b3, att_logit,
                                        (float*)d_out);
}

// Round 16
// 404.829 us; speedup vs baseline: 1.0758x; 1.0758x over previous
//
#include <hip/hip_runtime.h>
#include <hip/hip_bf16.h>

// AutoInt+MLP fused forward, MI355X gfx950.  Round 16:
//  - dnn : FROZEN at round-10 shape (r14 512-thr and r15 paired-field both
//          regressed; 256 thr / M=32 / C1[2][8] / 39-iter dbuf is the optimum).
//  - attn: 1 sample per block, 2 waves (was 2 samples / 4 waves). Same data path,
//          same per-wave work; barrier groups shrink 4->2 waves and 6 blocks/CU
//          (25.9KB LDS) gives 6 independent scheduling domains per CU.
//  HARD RULES: no 2-arg __launch_bounds__ (r5/8/9 corrupt, r6 spill); no
//  heterogeneous-role merged dispatch (r11); dnn M=64 spills (r6/r12).

#define NF     39
#define EMB    64
#define NLAYER 3
#define VOCAB  1000
#define FLAT   2496
#define H1     512
#define H2     256

typedef __attribute__((ext_vector_type(8))) short  short8;
typedef __attribute__((ext_vector_type(4))) float  floatx4;

__device__ __forceinline__ short8 ld8s(const unsigned short* p) {
    return *(const short8*)p;
}
__device__ __forceinline__ float b2f(unsigned short h) {
    union { unsigned u; float f; } x; x.u = ((unsigned)h) << 16; return x.f;
}
__device__ __forceinline__ unsigned short f2b(float f) {
    union { float f; unsigned u; } x; x.f = f;
    unsigned u = x.u;
    return (unsigned short)((u + 0x7fffu + ((u >> 16) & 1u)) >> 16);
}
// 2 floats -> packed bf16x2 in ONE VALU op (gfx950 hw cvt, RNE)
__device__ __forceinline__ unsigned cvt_pk(float a, float b) {
#if defined(__gfx950__)
    unsigned r;
    asm("v_cvt_pk_bf16_f32 %0, %1, %2" : "=v"(r) : "v"(a), "v"(b));
    return r;
#else
    return (unsigned)f2b(a) | ((unsigned)f2b(b) << 16);
#endif
}

// ------- prep: attention weights f32 [L][64(k)][64(o)] -> bf16 [L][o][k] --------------
__global__ void attw_t(const float* __restrict__ WQ, const float* __restrict__ WK,
                       const float* __restrict__ WV, const float* __restrict__ WR,
                       unsigned short* __restrict__ wqt, unsigned short* __restrict__ wkt,
                       unsigned short* __restrict__ wvt, unsigned short* __restrict__ wrt)
{
    int idx = blockIdx.x * 256 + threadIdx.x;       // 4*3*4096 = 49152
    if (idx >= 4 * 3 * 4096) return;
    int mat = idx / 12288;
    int rem = idx % 12288;
    int l   = rem / 4096;
    int ok  = rem % 4096;
    int o = ok >> 6, k = ok & 63;
    const float*    src = (mat == 0) ? WQ : (mat == 1) ? WK : (mat == 2) ? WV : WR;
    unsigned short* dst = (mat == 0) ? wqt : (mat == 1) ? wkt : (mat == 2) ? wvt : wrt;
    dst[l * 4096 + o * 64 + k] = f2b(src[l * 4096 + k * 64 + o]);
}

// ------- prep: W1 f32 [2496][512] -> bf16 fragment-linear w1p --------------------------
__global__ void w1pack(const float* __restrict__ W1, unsigned short* __restrict__ w1p)
{
    int t = blockIdx.x * 256 + threadIdx.x;        // 624*256 = 159744 = 2496*64
    int lane = t & 63, grp = t >> 6;               // grp 0..2495
    int ot = grp / 78, kk = grp % 78;
    int q = lane >> 4, n = ot * 16 + (lane & 15);
    int kb = kk * 32 + q * 8;
    unsigned short* dst = w1p + grp * 512 + lane * 8;
    #pragma unroll
    for (int j = 0; j < 8; ++j)
        dst[j] = f2b(W1[(kb + j) * 512 + n]);
}

// ------- prep: W2 f32 [512][256] -> bf16 fragment-linear w2p ---------------------------
__global__ void w2pack(const float* __restrict__ W2, unsigned short* __restrict__ w2p)
{
    int t = blockIdx.x * 256 + threadIdx.x;        // 64*256 = 16384 = 256*64
    int lane = t & 63, grp = t >> 6;               // grp 0..255
    int ot = grp / 16, kk = grp % 16;
    int q = lane >> 4, n = ot * 16 + (lane & 15);
    int kb = kk * 32 + q * 8;
    unsigned short* dst = w2p + grp * 512 + lane * 8;
    #pragma unroll
    for (int j = 0; j < 8; ++j)
        dst[j] = f2b(W2[(kb + j) * 256 + n]);
}

// ------- fused attention: 1 sample/block, 2 waves (wave = head) -----------------------
// 16384 blocks x 128 thr. LDS: xss 6912 + arena 2x9472 + red 8 = 25864 B
// -> 6 blocks/CU (12 waves/CU), barrier groups of 2 waves.
__global__ void __launch_bounds__(128) attn_kernel(
    const int* __restrict__ X,
    const float* __restrict__ embf,
    const unsigned short* __restrict__ wqt,
    const unsigned short* __restrict__ wkt,
    const unsigned short* __restrict__ wvt,
    const unsigned short* __restrict__ wrt,
    const float* __restrict__ wlinf,
    float* __restrict__ att_out)
{
    __shared__ unsigned short xss[48 * 72];        // [token 48][col 64+8pad]
    __shared__ unsigned short arena[2][4736];
    __shared__ float red[2];

    const int tid  = threadIdx.x;
    const int wid  = tid >> 6;          // 0..1
    const int lane = tid & 63;
    const int h    = wid;               // head
    const int quad = lane >> 4;
    const int l16  = lane & 15;
    const int samp = blockIdx.x;

    unsigned short* qs  = arena[wid];
    unsigned short* ks  = qs + 1920;
    unsigned short* Ps  = qs;           // alias (qs/ks dead after S^T)
    unsigned short* vt  = qs + 3456;    // 32 x 40 (toks of one K-half)

    // ---- embedding gather: wave fills its head's cols h*32..h*32+31 -------------------
    {
        const int tq = lane >> 4;            // 0..3
        const int cp = (lane & 15) * 2;      // 0,2,..,30
        const int col = h * 32 + cp;
        const int* xrow = X + samp * NF;
        #pragma unroll
        for (int t0 = 0; t0 < 48; t0 += 4) {
            int t = t0 + tq;
            unsigned pk = 0;
            if (t < NF) {
                int row = xrow[t] + t * VOCAB;
                const float2 v = *(const float2*)&embf[row * EMB + col];
                pk = cvt_pk(v.x, v.y);
            }
            *(unsigned*)&xss[t * 72 + col] = pk;   // rows 39..47 zeroed
        }
    }
    __syncthreads();

    for (int layer = 0; layer < NLAYER; ++layer) {
        const unsigned short* wq  = wqt + layer * 4096;
        const unsigned short* wk  = wkt + layer * 4096;
        const unsigned short* wvp = wvt + layer * 4096;
        const unsigned short* wr  = wrt + layer * 4096;

        // ---- Q,K projections, transposed orientation: C = W^T @ x^T -------------------
        #pragma unroll
        for (int mat = 0; mat < 2; ++mat) {
            const unsigned short* wt = mat ? wk : wq;
            unsigned short* dst = mat ? ks : qs;
            #pragma unroll
            for (int ot = 0; ot < 2; ++ot) {
                #pragma unroll
                for (int tt = 0; tt < 3; ++tt) {
                    floatx4 c = {0.f, 0.f, 0.f, 0.f};
                    #pragma unroll
                    for (int kk = 0; kk < 2; ++kk) {
                        short8 a = ld8s(&wt[(h * 32 + ot * 16 + l16) * 64 + kk * 32 + quad * 8]);
                        short8 b = ld8s(&xss[(tt * 16 + l16) * 72 + kk * 32 + quad * 8]);
                        c = __builtin_amdgcn_mfma_f32_16x16x32_bf16(a, b, c, 0, 0, 0);
                    }
                    uint2 w;
                    w.x = cvt_pk(c[0], c[1]);
                    w.y = cvt_pk(c[2], c[3]);
                    *(uint2*)&dst[(tt * 16 + l16) * 40 + ot * 16 + quad * 4] = w;
                }
            }
        }

        // ---- S^T = K @ Q^T  (C row = j, col = i) --------------------------------------
        floatx4 ST[3][3];
        #pragma unroll
        for (int jt = 0; jt < 3; ++jt) {
            short8 a = ld8s(&ks[(jt * 16 + l16) * 40 + quad * 8]);
            #pragma unroll
            for (int it = 0; it < 3; ++it) {
                short8 b = ld8s(&qs[(it * 16 + l16) * 40 + quad * 8]);
                floatx4 z = {0.f, 0.f, 0.f, 0.f};
                ST[jt][it] = __builtin_amdgcn_mfma_f32_16x16x32_bf16(a, b, z, 0, 0, 0);
            }
        }

        // ---- softmax over j (local + shfl_xor 16,32); write P in [i][j] to Ps ---------
        #pragma unroll
        for (int it = 0; it < 3; ++it) {
            float p[3][4];
            float sum = 0.f;
            #pragma unroll
            for (int jt = 0; jt < 3; ++jt)
                #pragma unroll
                for (int r = 0; r < 4; ++r) {
                    int j = jt * 16 + quad * 4 + r;
                    float e = (j < NF) ? __expf(ST[jt][it][r]) : 0.f;
                    p[jt][r] = e;
                    sum += e;
                }
            sum += __shfl_xor(sum, 16, 64);
            sum += __shfl_xor(sum, 32, 64);
            float inv = 1.0f / sum;
            #pragma unroll
            for (int jt = 0; jt < 3; ++jt) {
                uint2 w;
                w.x = cvt_pk(p[jt][0] * inv, p[jt][1] * inv);
                w.y = cvt_pk(p[jt][2] * inv, p[jt][3] * inv);
                *(uint2*)&Ps[(it * 16 + l16) * 72 + jt * 16 + quad * 4] = w;
            }
            uint2 z2; z2.x = 0; z2.y = 0;                 // zero K-pad cols 48..63
            *(uint2*)&Ps[(it * 16 + l16) * 72 + 48 + quad * 4] = z2;
        }

        // ---- V projection: mt=0,1 -> vT (toks 0..31); mt=2 held in regs ---------------
        unsigned sv[2][2];      // [nt][lo/hi] packed mt=2 C-frag (toks 32..47)
        #pragma unroll
        for (int mt = 0; mt < 3; ++mt) {
            #pragma unroll
            for (int nt = 0; nt < 2; ++nt) {
                floatx4 c = {0.f, 0.f, 0.f, 0.f};
                #pragma unroll
                for (int kk = 0; kk < 2; ++kk) {
                    short8 a = ld8s(&xss[(mt * 16 + l16) * 72 + kk * 32 + quad * 8]);
                    short8 b = ld8s(&wvp[(h * 32 + nt * 16 + l16) * 64 + kk * 32 + quad * 8]);
                    c = __builtin_amdgcn_mfma_f32_16x16x32_bf16(a, b, c, 0, 0, 0);
                }
                unsigned lo = cvt_pk(c[0], c[1]);
                unsigned hi = cvt_pk(c[2], c[3]);
                if (mt < 2) {
                    uint2 w; w.x = lo; w.y = hi;      // vT[d][tok_local mt*16+quad*4 ..+3]
                    *(uint2*)&vt[(nt * 16 + l16) * 40 + mt * 16 + quad * 4] = w;
                } else {
                    sv[nt][0] = lo; sv[nt][1] = hi;
                }
            }
        }

        // ---- R projection, transposed: O^T init (row = d, col = tok) ------------------
        floatx4 O[2][3];        // [dt][it]
        #pragma unroll
        for (int dt = 0; dt < 2; ++dt) {
            #pragma unroll
            for (int it = 0; it < 3; ++it) {
                floatx4 c = {0.f, 0.f, 0.f, 0.f};
                #pragma unroll
                for (int kk = 0; kk < 2; ++kk) {
                    short8 a = ld8s(&wr[(h * 32 + dt * 16 + l16) * 64 + kk * 32 + quad * 8]);
                    short8 b = ld8s(&xss[(it * 16 + l16) * 72 + kk * 32 + quad * 8]);
                    c = __builtin_amdgcn_mfma_f32_16x16x32_bf16(a, b, c, 0, 0, 0);
                }
                O[dt][it] = c;
            }
        }

        __syncthreads();   // both waves done reading xss

        // ---- O^T += V^T @ P^T, kk=0 (toks 0..31): A = vt, B = Ps ----------------------
        {
            short8 b0 = ld8s(&Ps[(l16) * 72 + quad * 8]);
            short8 b1 = ld8s(&Ps[(16 + l16) * 72 + quad * 8]);
            short8 b2 = ld8s(&Ps[(32 + l16) * 72 + quad * 8]);
            #pragma unroll
            for (int dt = 0; dt < 2; ++dt) {
                short8 a = ld8s(&vt[(dt * 16 + l16) * 40 + quad * 8]);
                O[dt][0] = __builtin_amdgcn_mfma_f32_16x16x32_bf16(a, b0, O[dt][0], 0, 0, 0);
                O[dt][1] = __builtin_amdgcn_mfma_f32_16x16x32_bf16(a, b1, O[dt][1], 0, 0, 0);
                O[dt][2] = __builtin_amdgcn_mfma_f32_16x16x32_bf16(a, b2, O[dt][2], 0, 0, 0);
            }
        }
        // ---- refill vT with toks 32..63 (local 0..15 = sv, 16..31 = zeros) ------------
        #pragma unroll
        for (int nt = 0; nt < 2; ++nt) {
            uint2 w; w.x = sv[nt][0]; w.y = sv[nt][1];
            *(uint2*)&vt[(nt * 16 + l16) * 40 + quad * 4] = w;
            uint2 z; z.x = 0; z.y = 0;
            *(uint2*)&vt[(nt * 16 + l16) * 40 + 16 + quad * 4] = z;
        }
        // ---- O^T += V^T @ P^T, kk=1 (toks 32..63) -------------------------------------
        {
            short8 b0 = ld8s(&Ps[(l16) * 72 + 32 + quad * 8]);
            short8 b1 = ld8s(&Ps[(16 + l16) * 72 + 32 + quad * 8]);
            short8 b2 = ld8s(&Ps[(32 + l16) * 72 + 32 + quad * 8]);
            #pragma unroll
            for (int dt = 0; dt < 2; ++dt) {
                short8 a = ld8s(&vt[(dt * 16 + l16) * 40 + quad * 8]);
                O[dt][0] = __builtin_amdgcn_mfma_f32_16x16x32_bf16(a, b0, O[dt][0], 0, 0, 0);
                O[dt][1] = __builtin_amdgcn_mfma_f32_16x16x32_bf16(a, b1, O[dt][1], 0, 0, 0);
                O[dt][2] = __builtin_amdgcn_mfma_f32_16x16x32_bf16(a, b2, O[dt][2], 0, 0, 0);
            }
        }

        // ---- next x = relu(O^T): write xss[tok][d] with b64 of 4 consecutive d --------
        #pragma unroll
        for (int dt = 0; dt < 2; ++dt)
            #pragma unroll
            for (int it = 0; it < 3; ++it) {
                uint2 w;
                w.x = cvt_pk(fmaxf(O[dt][it][0], 0.f), fmaxf(O[dt][it][1], 0.f));
                w.y = cvt_pk(fmaxf(O[dt][it][2], 0.f), fmaxf(O[dt][it][3], 0.f));
                *(uint2*)&xss[(it * 16 + l16) * 72 + h * 32 + dt * 16 + quad * 4] = w;
            }

        __syncthreads();
    }

    // ---- att logit: relu( att_flat . Wlin ) -------------------------------------------
    {
        float acc = 0.f;
        const int c = lane & 31, tp = lane >> 5;
        const int col = h * 32 + c;
        for (int t0 = 0; t0 < 40; t0 += 2) {
            int t = t0 + tp;
            if (t < NF)
                acc += b2f(xss[t * 72 + col]) * wlinf[t * EMB + col];
        }
        #pragma unroll
        for (int off = 1; off < 64; off <<= 1)
            acc += __shfl_xor(acc, off, 64);
        if (lane == 0) red[wid] = acc;
        __syncthreads();
        if (tid == 0)
            att_out[samp] = fmaxf(red[0] + red[1], 0.f);
    }
}

// ------- DNN (ROUND-10 VERBATIM, frozen optimum): 32-sample tile, packed B-loads ------
// 512 blocks x 256 thr. LDS: ea 9216 + h1s 33280 = 42496 B.
__global__ void __launch_bounds__(256) dnn_kernel(
    const int* __restrict__ X,
    const float* __restrict__ embf,
    const unsigned short* __restrict__ w1p,
    const float* __restrict__ b1v,
    const unsigned short* __restrict__ w2p,
    const float* __restrict__ b2v,
    const float* __restrict__ w3v,
    const float* __restrict__ b3v,
    const float* __restrict__ att_in,
    float* __restrict__ out)
{
    __shared__ unsigned short ea[2][32 * 72];     // double-buffered [sample 32][64+8pad]
    __shared__ unsigned short h1s[32 * 520];      // h1 [32][512+8pad]; h2 [32][264] aliases
    unsigned short* h2s = h1s;

    const int tid  = threadIdx.x;
    const int wid  = tid >> 6, lane = tid & 63, quad = lane >> 4, l16 = lane & 15;
    const int S0   = blockIdx.x * 32;

    floatx4 C1[2][8];
    #pragma unroll
    for (int mt = 0; mt < 2; ++mt)
        #pragma unroll
        for (int nt = 0; nt < 8; ++nt)
            C1[mt][nt] = (floatx4){0.f, 0.f, 0.f, 0.f};

    const int gs = tid >> 3;        // 0..31 sample for staging
    const int gg = tid & 7;         // 8 floats each

    // prologue: stage field 0 into ea[0]
    {
        int row = X[(S0 + gs) * NF + 0];
        const float4* src = (const float4*)&embf[row * EMB + gg * 8];
        float4 v0 = src[0], v1 = src[1];
        uint4 u;
        u.x = cvt_pk(v0.x, v0.y); u.y = cvt_pk(v0.z, v0.w);
        u.z = cvt_pk(v1.x, v1.y); u.w = cvt_pk(v1.z, v1.w);
        *(uint4*)&ea[0][gs * 72 + gg * 8] = u;
    }
    __syncthreads();

    // ---- phase 1: h1 = emb(32 x 2496) @ W1, K streamed per field, dbuf, 1 sync/iter ---
    for (int f = 0; f < NF; ++f) {
        if (f < NF - 1) {   // stage next field into the other buffer (disjoint from reads)
            int row = X[(S0 + gs) * NF + f + 1] + (f + 1) * VOCAB;
            const float4* src = (const float4*)&embf[row * EMB + gg * 8];
            float4 v0 = src[0], v1 = src[1];
            uint4 u;
            u.x = cvt_pk(v0.x, v0.y); u.y = cvt_pk(v0.z, v0.w);
            u.z = cvt_pk(v1.x, v1.y); u.w = cvt_pk(v1.z, v1.w);
            *(uint4*)&ea[(f + 1) & 1][gs * 72 + gg * 8] = u;
        }
        const unsigned short* eac = ea[f & 1];
        short8 a[2][2];
        #pragma unroll
        for (int mt = 0; mt < 2; ++mt) {
            a[mt][0] = ld8s(&eac[(mt * 16 + l16) * 72 + quad * 8]);
            a[mt][1] = ld8s(&eac[(mt * 16 + l16) * 72 + 32 + quad * 8]);
        }
        #pragma unroll
        for (int nt = 0; nt < 8; ++nt) {
            const unsigned short* bp = w1p + (((wid * 8 + nt) * 78 + f * 2) * 64 + lane) * 8;
            short8 b0 = ld8s(bp);
            short8 b1 = ld8s(bp + 512);
            #pragma unroll
            for (int mt = 0; mt < 2; ++mt) {
                C1[mt][nt] = __builtin_amdgcn_mfma_f32_16x16x32_bf16(a[mt][0], b0, C1[mt][nt], 0, 0, 0);
                C1[mt][nt] = __builtin_amdgcn_mfma_f32_16x16x32_bf16(a[mt][1], b1, C1[mt][nt], 0, 0, 0);
            }
        }
        __syncthreads();   // waves may not drift >1 iter: protects both ea buffers
    }

    // bias + relu, write ALL of h1 to LDS (each wave owns 128 cols)
    #pragma unroll
    for (int nt = 0; nt < 8; ++nt) {
        float bb = b1v[wid * 128 + nt * 16 + l16];
        #pragma unroll
        for (int mt = 0; mt < 2; ++mt) {
            #pragma unroll
            for (int r = 0; r < 4; ++r) {
                float v = fmaxf(C1[mt][nt][r] + bb, 0.f);
                h1s[(mt * 16 + quad * 4 + r) * 520 + wid * 128 + nt * 16 + l16] = f2b(v);
            }
        }
    }
    __syncthreads();

    // ---- phase 2: h2 = h1(32 x 512) @ W2, single pass, wave owns 64 N-cols ------------
    floatx4 C2[2][4];
    #pragma unroll
    for (int mt = 0; mt < 2; ++mt)
        #pragma unroll
        for (int nt = 0; nt < 4; ++nt)
            C2[mt][nt] = (floatx4){0.f, 0.f, 0.f, 0.f};

    #pragma unroll 4
    for (int kk = 0; kk < 16; ++kk) {
        short8 a0 = ld8s(&h1s[(l16) * 520 + kk * 32 + quad * 8]);
        short8 a1 = ld8s(&h1s[(16 + l16) * 520 + kk * 32 + quad * 8]);
        #pragma unroll
        for (int nt = 0; nt < 4; ++nt) {
            short8 b = ld8s(w2p + (((wid * 4 + nt) * 16 + kk) * 64 + lane) * 8);
            C2[0][nt] = __builtin_amdgcn_mfma_f32_16x16x32_bf16(a0, b, C2[0][nt], 0, 0, 0);
            C2[1][nt] = __builtin_amdgcn_mfma_f32_16x16x32_bf16(a1, b, C2[1][nt], 0, 0, 0);
        }
    }
    __syncthreads();    // h1 reads complete -> safe to alias h2s onto h1s

    #pragma unroll
    for (int nt = 0; nt < 4; ++nt) {
        float bb = b2v[wid * 64 + nt * 16 + l16];
        #pragma unroll
        for (int mt = 0; mt < 2; ++mt)
            #pragma unroll
            for (int r = 0; r < 4; ++r)
                h2s[(mt * 16 + quad * 4 + r) * 264 + wid * 64 + nt * 16 + l16] =
                    f2b(fmaxf(C2[mt][nt][r] + bb, 0.f));
    }
    __syncthreads();

    // ---- phase 3: dnn = relu(h2 . W3 + b3); out = sigmoid(att + dnn), f32 -------------
    {
        int s = tid >> 3, part = tid & 7;     // 8 lanes per sample, 32 elems each
        float acc = 0.f;
        #pragma unroll 8
        for (int j = 0; j < 32; ++j) {
            int jj = part * 32 + j;
            acc += b2f(h2s[s * 264 + jj]) * w3v[jj];
        }
        acc += __shfl_xor(acc, 1, 64);
        acc += __shfl_xor(acc, 2, 64);
        acc += __shfl_xor(acc, 4, 64);
        if (part == 0) {
            float dnn = fmaxf(acc + b3v[0], 0.f);
            float v = dnn + att_in[S0 + s];
            out[S0 + s] = 1.f / (1.f + __expf(-v));
        }
    }
}

extern "C" void kernel_launch(void* const* d_in, const int* in_sizes, int n_in,
                              void* d_out, int out_size, void* d_ws, size_t ws_size,
                              hipStream_t stream)
{
    (void)in_sizes; (void)n_in; (void)out_size; (void)ws_size;

    const int*   X    = (const int*)d_in[0];
    const float* emb  = (const float*)d_in[1];
    const float* WQ   = (const float*)d_in[2];
    const float* WK   = (const float*)d_in[3];
    const float* WV   = (const float*)d_in[4];
    const float* WR   = (const float*)d_in[5];
    const float* W1   = (const float*)d_in[6];
    const float* b1   = (const float*)d_in[7];
    const float* W2   = (const float*)d_in[8];
    const float* b2   = (const float*)d_in[9];
    const float* W3   = (const float*)d_in[10];
    const float* b3   = (const float*)d_in[11];
    const float* Wlin = (const float*)d_in[12];

    char* ws = (char*)d_ws;
    float*          att_logit = (float*)ws;                          // 16384 f32 = 64KB
    unsigned short* wqt = (unsigned short*)(ws + 65536);             // 3*4096 shorts each
    unsigned short* wkt = wqt + 3 * 4096;
    unsigned short* wvt = wkt + 3 * 4096;
    unsigned short* wrt = wvt + 3 * 4096;
    unsigned short* w1p = wrt + 3 * 4096;                            // 2496*512 shorts
    unsigned short* w2p = w1p + 2496 * 512;                          // 256*512 shorts

    attw_t<<<192, 256, 0, stream>>>(WQ, WK, WV, WR, wqt, wkt, wvt, wrt);
    w1pack<<<624, 256, 0, stream>>>(W1, w1p);
    w2pack<<<64, 256, 0, stream>>>(W2, w2p);
    attn_kernel<<<16384, 128, 0, stream>>>(X, emb, wqt, wkt, wvt, wrt, Wlin, att_logit);
    dnn_kernel<<<512, 256, 0, stream>>>(X, emb, w1p, b1, w2p, b2, W3, b3, att_logit,
                                        (float*)d_out);
}

// Round 17
// 401.470 us; speedup vs baseline: 1.0848x; 1.0084x over previous
//
#include <hip/hip_runtime.h>
#include <hip/hip_bf16.h>

// AutoInt+MLP fused forward, MI355X gfx950.  Round 17:
//  - attn: ILP reorder inside the layer loop. R-projection (12 independent MFMAs,
//          reads only xss+wr) moved between Q/K-proj and S^T to cover the qs/ks
//          ds_write->ds_read bubble; the xss-read barrier slid down to just before
//          the x-writeback (V-proj is the last xss reader; S^T/softmax/PV are
//          wave-private). Aliasing order preserved: softmax writes Ps(=qs) after
//          S^T reads qs; V writes vt (overlaps ks tail) after S^T reads ks.
//  - dnn : frozen round-10 optimum.
//  HARD RULES: no 2-arg __launch_bounds__; no merged heterogeneous dispatch;
//  dnn M=64 spills; dnn 512-thr & paired-field regress.

#define NF     39
#define EMB    64
#define NLAYER 3
#define VOCAB  1000
#define FLAT   2496
#define H1     512
#define H2     256

typedef __attribute__((ext_vector_type(8))) short  short8;
typedef __attribute__((ext_vector_type(4))) float  floatx4;

__device__ __forceinline__ short8 ld8s(const unsigned short* p) {
    return *(const short8*)p;
}
__device__ __forceinline__ float b2f(unsigned short h) {
    union { unsigned u; float f; } x; x.u = ((unsigned)h) << 16; return x.f;
}
__device__ __forceinline__ unsigned short f2b(float f) {
    union { float f; unsigned u; } x; x.f = f;
    unsigned u = x.u;
    return (unsigned short)((u + 0x7fffu + ((u >> 16) & 1u)) >> 16);
}
// 2 floats -> packed bf16x2 in ONE VALU op (gfx950 hw cvt, RNE)
__device__ __forceinline__ unsigned cvt_pk(float a, float b) {
#if defined(__gfx950__)
    unsigned r;
    asm("v_cvt_pk_bf16_f32 %0, %1, %2" : "=v"(r) : "v"(a), "v"(b));
    return r;
#else
    return (unsigned)f2b(a) | ((unsigned)f2b(b) << 16);
#endif
}

// ------- prep: attention weights f32 [L][64(k)][64(o)] -> bf16 [L][o][k] --------------
__global__ void attw_t(const float* __restrict__ WQ, const float* __restrict__ WK,
                       const float* __restrict__ WV, const float* __restrict__ WR,
                       unsigned short* __restrict__ wqt, unsigned short* __restrict__ wkt,
                       unsigned short* __restrict__ wvt, unsigned short* __restrict__ wrt)
{
    int idx = blockIdx.x * 256 + threadIdx.x;       // 4*3*4096 = 49152
    if (idx >= 4 * 3 * 4096) return;
    int mat = idx / 12288;
    int rem = idx % 12288;
    int l   = rem / 4096;
    int ok  = rem % 4096;
    int o = ok >> 6, k = ok & 63;
    const float*    src = (mat == 0) ? WQ : (mat == 1) ? WK : (mat == 2) ? WV : WR;
    unsigned short* dst = (mat == 0) ? wqt : (mat == 1) ? wkt : (mat == 2) ? wvt : wrt;
    dst[l * 4096 + o * 64 + k] = f2b(src[l * 4096 + k * 64 + o]);
}

// ------- prep: W1 f32 [2496][512] -> bf16 fragment-linear w1p --------------------------
__global__ void w1pack(const float* __restrict__ W1, unsigned short* __restrict__ w1p)
{
    int t = blockIdx.x * 256 + threadIdx.x;        // 624*256 = 159744 = 2496*64
    int lane = t & 63, grp = t >> 6;               // grp 0..2495
    int ot = grp / 78, kk = grp % 78;
    int q = lane >> 4, n = ot * 16 + (lane & 15);
    int kb = kk * 32 + q * 8;
    unsigned short* dst = w1p + grp * 512 + lane * 8;
    #pragma unroll
    for (int j = 0; j < 8; ++j)
        dst[j] = f2b(W1[(kb + j) * 512 + n]);
}

// ------- prep: W2 f32 [512][256] -> bf16 fragment-linear w2p ---------------------------
__global__ void w2pack(const float* __restrict__ W2, unsigned short* __restrict__ w2p)
{
    int t = blockIdx.x * 256 + threadIdx.x;        // 64*256 = 16384 = 256*64
    int lane = t & 63, grp = t >> 6;               // grp 0..255
    int ot = grp / 16, kk = grp % 16;
    int q = lane >> 4, n = ot * 16 + (lane & 15);
    int kb = kk * 32 + q * 8;
    unsigned short* dst = w2p + grp * 512 + lane * 8;
    #pragma unroll
    for (int j = 0; j < 8; ++j)
        dst[j] = f2b(W2[(kb + j) * 256 + n]);
}

// ------- fused attention: 1 sample/block, 2 waves (wave = head) -----------------------
// 16384 blocks x 128 thr. LDS: xss 6912 + arena 2x9472 + red 8 = 25864 B
// -> 6 blocks/CU, barrier groups of 2 waves.
__global__ void __launch_bounds__(128) attn_kernel(
    const int* __restrict__ X,
    const float* __restrict__ embf,
    const unsigned short* __restrict__ wqt,
    const unsigned short* __restrict__ wkt,
    const unsigned short* __restrict__ wvt,
    const unsigned short* __restrict__ wrt,
    const float* __restrict__ wlinf,
    float* __restrict__ att_out)
{
    __shared__ unsigned short xss[48 * 72];        // [token 48][col 64+8pad]
    __shared__ unsigned short arena[2][4736];
    __shared__ float red[2];

    const int tid  = threadIdx.x;
    const int wid  = tid >> 6;          // 0..1
    const int lane = tid & 63;
    const int h    = wid;               // head
    const int quad = lane >> 4;
    const int l16  = lane & 15;
    const int samp = blockIdx.x;

    unsigned short* qs  = arena[wid];
    unsigned short* ks  = qs + 1920;
    unsigned short* Ps  = qs;           // alias (qs/ks dead after S^T)
    unsigned short* vt  = qs + 3456;    // 32 x 40 (toks of one K-half)

    // ---- embedding gather: wave fills its head's cols h*32..h*32+31 -------------------
    {
        const int tq = lane >> 4;            // 0..3
        const int cp = (lane & 15) * 2;      // 0,2,..,30
        const int col = h * 32 + cp;
        const int* xrow = X + samp * NF;
        #pragma unroll
        for (int t0 = 0; t0 < 48; t0 += 4) {
            int t = t0 + tq;
            unsigned pk = 0;
            if (t < NF) {
                int row = xrow[t] + t * VOCAB;
                const float2 v = *(const float2*)&embf[row * EMB + col];
                pk = cvt_pk(v.x, v.y);
            }
            *(unsigned*)&xss[t * 72 + col] = pk;   // rows 39..47 zeroed
        }
    }
    __syncthreads();

    for (int layer = 0; layer < NLAYER; ++layer) {
        const unsigned short* wq  = wqt + layer * 4096;
        const unsigned short* wk  = wkt + layer * 4096;
        const unsigned short* wvp = wvt + layer * 4096;
        const unsigned short* wr  = wrt + layer * 4096;

        // ---- Q,K projections, transposed orientation: C = W^T @ x^T -------------------
        #pragma unroll
        for (int mat = 0; mat < 2; ++mat) {
            const unsigned short* wt = mat ? wk : wq;
            unsigned short* dst = mat ? ks : qs;
            #pragma unroll
            for (int ot = 0; ot < 2; ++ot) {
                #pragma unroll
                for (int tt = 0; tt < 3; ++tt) {
                    floatx4 c = {0.f, 0.f, 0.f, 0.f};
                    #pragma unroll
                    for (int kk = 0; kk < 2; ++kk) {
                        short8 a = ld8s(&wt[(h * 32 + ot * 16 + l16) * 64 + kk * 32 + quad * 8]);
                        short8 b = ld8s(&xss[(tt * 16 + l16) * 72 + kk * 32 + quad * 8]);
                        c = __builtin_amdgcn_mfma_f32_16x16x32_bf16(a, b, c, 0, 0, 0);
                    }
                    uint2 w;
                    w.x = cvt_pk(c[0], c[1]);
                    w.y = cvt_pk(c[2], c[3]);
                    *(uint2*)&dst[(tt * 16 + l16) * 40 + ot * 16 + quad * 4] = w;
                }
            }
        }

        // ---- R projection (moved up: 12 independent MFMAs cover qs/ks write->read) ----
        floatx4 O[2][3];        // [dt][it]
        #pragma unroll
        for (int dt = 0; dt < 2; ++dt) {
            #pragma unroll
            for (int it = 0; it < 3; ++it) {
                floatx4 c = {0.f, 0.f, 0.f, 0.f};
                #pragma unroll
                for (int kk = 0; kk < 2; ++kk) {
                    short8 a = ld8s(&wr[(h * 32 + dt * 16 + l16) * 64 + kk * 32 + quad * 8]);
                    short8 b = ld8s(&xss[(it * 16 + l16) * 72 + kk * 32 + quad * 8]);
                    c = __builtin_amdgcn_mfma_f32_16x16x32_bf16(a, b, c, 0, 0, 0);
                }
                O[dt][it] = c;
            }
        }

        // ---- S^T = K @ Q^T  (C row = j, col = i) --------------------------------------
        floatx4 ST[3][3];
        #pragma unroll
        for (int jt = 0; jt < 3; ++jt) {
            short8 a = ld8s(&ks[(jt * 16 + l16) * 40 + quad * 8]);
            #pragma unroll
            for (int it = 0; it < 3; ++it) {
                short8 b = ld8s(&qs[(it * 16 + l16) * 40 + quad * 8]);
                floatx4 z = {0.f, 0.f, 0.f, 0.f};
                ST[jt][it] = __builtin_amdgcn_mfma_f32_16x16x32_bf16(a, b, z, 0, 0, 0);
            }
        }

        // ---- softmax over j (local + shfl_xor 16,32); write P in [i][j] to Ps ---------
        // (Ps aliases qs: safe, S^T already consumed qs; wave-private DS is in-order)
        #pragma unroll
        for (int it = 0; it < 3; ++it) {
            float p[3][4];
            float sum = 0.f;
            #pragma unroll
            for (int jt = 0; jt < 3; ++jt)
                #pragma unroll
                for (int r = 0; r < 4; ++r) {
                    int j = jt * 16 + quad * 4 + r;
                    float e = (j < NF) ? __expf(ST[jt][it][r]) : 0.f;
                    p[jt][r] = e;
                    sum += e;
                }
            sum += __shfl_xor(sum, 16, 64);
            sum += __shfl_xor(sum, 32, 64);
            float inv = 1.0f / sum;
            #pragma unroll
            for (int jt = 0; jt < 3; ++jt) {
                uint2 w;
                w.x = cvt_pk(p[jt][0] * inv, p[jt][1] * inv);
                w.y = cvt_pk(p[jt][2] * inv, p[jt][3] * inv);
                *(uint2*)&Ps[(it * 16 + l16) * 72 + jt * 16 + quad * 4] = w;
            }
            uint2 z2; z2.x = 0; z2.y = 0;                 // zero K-pad cols 48..63
            *(uint2*)&Ps[(it * 16 + l16) * 72 + 48 + quad * 4] = z2;
        }

        // ---- V projection: mt=0,1 -> vT (toks 0..31); mt=2 held in regs ---------------
        // (vt overlaps ks tail: safe, S^T already consumed ks)
        unsigned sv[2][2];      // [nt][lo/hi] packed mt=2 C-frag (toks 32..47)
        #pragma unroll
        for (int mt = 0; mt < 3; ++mt) {
            #pragma unroll
            for (int nt = 0; nt < 2; ++nt) {
                floatx4 c = {0.f, 0.f, 0.f, 0.f};
                #pragma unroll
                for (int kk = 0; kk < 2; ++kk) {
                    short8 a = ld8s(&xss[(mt * 16 + l16) * 72 + kk * 32 + quad * 8]);
                    short8 b = ld8s(&wvp[(h * 32 + nt * 16 + l16) * 64 + kk * 32 + quad * 8]);
                    c = __builtin_amdgcn_mfma_f32_16x16x32_bf16(a, b, c, 0, 0, 0);
                }
                unsigned lo = cvt_pk(c[0], c[1]);
                unsigned hi = cvt_pk(c[2], c[3]);
                if (mt < 2) {
                    uint2 w; w.x = lo; w.y = hi;      // vT[d][tok_local mt*16+quad*4 ..+3]
                    *(uint2*)&vt[(nt * 16 + l16) * 40 + mt * 16 + quad * 4] = w;
                } else {
                    sv[nt][0] = lo; sv[nt][1] = hi;
                }
            }
        }

        // ---- O^T += V^T @ P^T, kk=0 (toks 0..31): A = vt, B = Ps ----------------------
        {
            short8 b0 = ld8s(&Ps[(l16) * 72 + quad * 8]);
            short8 b1 = ld8s(&Ps[(16 + l16) * 72 + quad * 8]);
            short8 b2 = ld8s(&Ps[(32 + l16) * 72 + quad * 8]);
            #pragma unroll
            for (int dt = 0; dt < 2; ++dt) {
                short8 a = ld8s(&vt[(dt * 16 + l16) * 40 + quad * 8]);
                O[dt][0] = __builtin_amdgcn_mfma_f32_16x16x32_bf16(a, b0, O[dt][0], 0, 0, 0);
                O[dt][1] = __builtin_amdgcn_mfma_f32_16x16x32_bf16(a, b1, O[dt][1], 0, 0, 0);
                O[dt][2] = __builtin_amdgcn_mfma_f32_16x16x32_bf16(a, b2, O[dt][2], 0, 0, 0);
            }
        }
        // ---- refill vT with toks 32..63 (local 0..15 = sv, 16..31 = zeros) ------------
        #pragma unroll
        for (int nt = 0; nt < 2; ++nt) {
            uint2 w; w.x = sv[nt][0]; w.y = sv[nt][1];
            *(uint2*)&vt[(nt * 16 + l16) * 40 + quad * 4] = w;
            uint2 z; z.x = 0; z.y = 0;
            *(uint2*)&vt[(nt * 16 + l16) * 40 + 16 + quad * 4] = z;
        }
        // ---- O^T += V^T @ P^T, kk=1 (toks 32..63) -------------------------------------
        {
            short8 b0 = ld8s(&Ps[(l16) * 72 + 32 + quad * 8]);
            short8 b1 = ld8s(&Ps[(16 + l16) * 72 + 32 + quad * 8]);
            short8 b2 = ld8s(&Ps[(32 + l16) * 72 + 32 + quad * 8]);
            #pragma unroll
            for (int dt = 0; dt < 2; ++dt) {
                short8 a = ld8s(&vt[(dt * 16 + l16) * 40 + quad * 8]);
                O[dt][0] = __builtin_amdgcn_mfma_f32_16x16x32_bf16(a, b0, O[dt][0], 0, 0, 0);
                O[dt][1] = __builtin_amdgcn_mfma_f32_16x16x32_bf16(a, b1, O[dt][1], 0, 0, 0);
                O[dt][2] = __builtin_amdgcn_mfma_f32_16x16x32_bf16(a, b2, O[dt][2], 0, 0, 0);
            }
        }

        __syncthreads();   // all xss reads (QK, R, V) complete in BOTH waves

        // ---- next x = relu(O^T): write xss[tok][d] with b64 of 4 consecutive d --------
        #pragma unroll
        for (int dt = 0; dt < 2; ++dt)
            #pragma unroll
            for (int it = 0; it < 3; ++it) {
                uint2 w;
                w.x = cvt_pk(fmaxf(O[dt][it][0], 0.f), fmaxf(O[dt][it][1], 0.f));
                w.y = cvt_pk(fmaxf(O[dt][it][2], 0.f), fmaxf(O[dt][it][3], 0.f));
                *(uint2*)&xss[(it * 16 + l16) * 72 + h * 32 + dt * 16 + quad * 4] = w;
            }

        __syncthreads();   // xss rewritten before next layer's reads
    }

    // ---- att logit: relu( att_flat . Wlin ) -------------------------------------------
    {
        float acc = 0.f;
        const int c = lane & 31, tp = lane >> 5;
        const int col = h * 32 + c;
        for (int t0 = 0; t0 < 40; t0 += 2) {
            int t = t0 + tp;
            if (t < NF)
                acc += b2f(xss[t * 72 + col]) * wlinf[t * EMB + col];
        }
        #pragma unroll
        for (int off = 1; off < 64; off <<= 1)
            acc += __shfl_xor(acc, off, 64);
        if (lane == 0) red[wid] = acc;
        __syncthreads();
        if (tid == 0)
            att_out[samp] = fmaxf(red[0] + red[1], 0.f);
    }
}

// ------- DNN (ROUND-10 VERBATIM, frozen optimum): 32-sample tile, packed B-loads ------
// 512 blocks x 256 thr. LDS: ea 9216 + h1s 33280 = 42496 B.
__global__ void __launch_bounds__(256) dnn_kernel(
    const int* __restrict__ X,
    const float* __restrict__ embf,
    const unsigned short* __restrict__ w1p,
    const float* __restrict__ b1v,
    const unsigned short* __restrict__ w2p,
    const float* __restrict__ b2v,
    const float* __restrict__ w3v,
    const float* __restrict__ b3v,
    const float* __restrict__ att_in,
    float* __restrict__ out)
{
    __shared__ unsigned short ea[2][32 * 72];     // double-buffered [sample 32][64+8pad]
    __shared__ unsigned short h1s[32 * 520];      // h1 [32][512+8pad]; h2 [32][264] aliases
    unsigned short* h2s = h1s;

    const int tid  = threadIdx.x;
    const int wid  = tid >> 6, lane = tid & 63, quad = lane >> 4, l16 = lane & 15;
    const int S0   = blockIdx.x * 32;

    floatx4 C1[2][8];
    #pragma unroll
    for (int mt = 0; mt < 2; ++mt)
        #pragma unroll
        for (int nt = 0; nt < 8; ++nt)
            C1[mt][nt] = (floatx4){0.f, 0.f, 0.f, 0.f};

    const int gs = tid >> 3;        // 0..31 sample for staging
    const int gg = tid & 7;         // 8 floats each

    // prologue: stage field 0 into ea[0]
    {
        int row = X[(S0 + gs) * NF + 0];
        const float4* src = (const float4*)&embf[row * EMB + gg * 8];
        float4 v0 = src[0], v1 = src[1];
        uint4 u;
        u.x = cvt_pk(v0.x, v0.y); u.y = cvt_pk(v0.z, v0.w);
        u.z = cvt_pk(v1.x, v1.y); u.w = cvt_pk(v1.z, v1.w);
        *(uint4*)&ea[0][gs * 72 + gg * 8] = u;
    }
    __syncthreads();

    // ---- phase 1: h1 = emb(32 x 2496) @ W1, K streamed per field, dbuf, 1 sync/iter ---
    for (int f = 0; f < NF; ++f) {
        if (f < NF - 1) {   // stage next field into the other buffer (disjoint from reads)
            int row = X[(S0 + gs) * NF + f + 1] + (f + 1) * VOCAB;
            const float4* src = (const float4*)&embf[row * EMB + gg * 8];
            float4 v0 = src[0], v1 = src[1];
            uint4 u;
            u.x = cvt_pk(v0.x, v0.y); u.y = cvt_pk(v0.z, v0.w);
            u.z = cvt_pk(v1.x, v1.y); u.w = cvt_pk(v1.z, v1.w);
            *(uint4*)&ea[(f + 1) & 1][gs * 72 + gg * 8] = u;
        }
        const unsigned short* eac = ea[f & 1];
        short8 a[2][2];
        #pragma unroll
        for (int mt = 0; mt < 2; ++mt) {
            a[mt][0] = ld8s(&eac[(mt * 16 + l16) * 72 + quad * 8]);
            a[mt][1] = ld8s(&eac[(mt * 16 + l16) * 72 + 32 + quad * 8]);
        }
        #pragma unroll
        for (int nt = 0; nt < 8; ++nt) {
            const unsigned short* bp = w1p + (((wid * 8 + nt) * 78 + f * 2) * 64 + lane) * 8;
            short8 b0 = ld8s(bp);
            short8 b1 = ld8s(bp + 512);
            #pragma unroll
            for (int mt = 0; mt < 2; ++mt) {
                C1[mt][nt] = __builtin_amdgcn_mfma_f32_16x16x32_bf16(a[mt][0], b0, C1[mt][nt], 0, 0, 0);
                C1[mt][nt] = __builtin_amdgcn_mfma_f32_16x16x32_bf16(a[mt][1], b1, C1[mt][nt], 0, 0, 0);
            }
        }
        __syncthreads();   // waves may not drift >1 iter: protects both ea buffers
    }

    // bias + relu, write ALL of h1 to LDS (each wave owns 128 cols)
    #pragma unroll
    for (int nt = 0; nt < 8; ++nt) {
        float bb = b1v[wid * 128 + nt * 16 + l16];
        #pragma unroll
        for (int mt = 0; mt < 2; ++mt) {
            #pragma unroll
            for (int r = 0; r < 4; ++r) {
                float v = fmaxf(C1[mt][nt][r] + bb, 0.f);
                h1s[(mt * 16 + quad * 4 + r) * 520 + wid * 128 + nt * 16 + l16] = f2b(v);
            }
        }
    }
    __syncthreads();

    // ---- phase 2: h2 = h1(32 x 512) @ W2, single pass, wave owns 64 N-cols ------------
    floatx4 C2[2][4];
    #pragma unroll
    for (int mt = 0; mt < 2; ++mt)
        #pragma unroll
        for (int nt = 0; nt < 4; ++nt)
            C2[mt][nt] = (floatx4){0.f, 0.f, 0.f, 0.f};

    #pragma unroll 4
    for (int kk = 0; kk < 16; ++kk) {
        short8 a0 = ld8s(&h1s[(l16) * 520 + kk * 32 + quad * 8]);
        short8 a1 = ld8s(&h1s[(16 + l16) * 520 + kk * 32 + quad * 8]);
        #pragma unroll
        for (int nt = 0; nt < 4; ++nt) {
            short8 b = ld8s(w2p + (((wid * 4 + nt) * 16 + kk) * 64 + lane) * 8);
            C2[0][nt] = __builtin_amdgcn_mfma_f32_16x16x32_bf16(a0, b, C2[0][nt], 0, 0, 0);
            C2[1][nt] = __builtin_amdgcn_mfma_f32_16x16x32_bf16(a1, b, C2[1][nt], 0, 0, 0);
        }
    }
    __syncthreads();    // h1 reads complete -> safe to alias h2s onto h1s

    #pragma unroll
    for (int nt = 0; nt < 4; ++nt) {
        float bb = b2v[wid * 64 + nt * 16 + l16];
        #pragma unroll
        for (int mt = 0; mt < 2; ++mt)
            #pragma unroll
            for (int r = 0; r < 4; ++r)
                h2s[(mt * 16 + quad * 4 + r) * 264 + wid * 64 + nt * 16 + l16] =
                    f2b(fmaxf(C2[mt][nt][r] + bb, 0.f));
    }
    __syncthreads();

    // ---- phase 3: dnn = relu(h2 . W3 + b3); out = sigmoid(att + dnn), f32 -------------
    {
        int s = tid >> 3, part = tid & 7;     // 8 lanes per sample, 32 elems each
        float acc = 0.f;
        #pragma unroll 8
        for (int j = 0; j < 32; ++j) {
            int jj = part * 32 + j;
            acc += b2f(h2s[s * 264 + jj]) * w3v[jj];
        }
        acc += __shfl_xor(acc, 1, 64);
        acc += __shfl_xor(acc, 2, 64);
        acc += __shfl_xor(acc, 4, 64);
        if (part == 0) {
            float dnn = fmaxf(acc + b3v[0], 0.f);
            float v = dnn + att_in[S0 + s];
            out[S0 + s] = 1.f / (1.f + __expf(-v));
        }
    }
}

extern "C" void kernel_launch(void* const* d_in, const int* in_sizes, int n_in,
                              void* d_out, int out_size, void* d_ws, size_t ws_size,
                              hipStream_t stream)
{
    (void)in_sizes; (void)n_in; (void)out_size; (void)ws_size;

    const int*   X    = (const int*)d_in[0];
    const float* emb  = (const float*)d_in[1];
    const float* WQ   = (const float*)d_in[2];
    const float* WK   = (const float*)d_in[3];
    const float* WV   = (const float*)d_in[4];
    const float* WR   = (const float*)d_in[5];
    const float* W1   = (const float*)d_in[6];
    const float* b1   = (const float*)d_in[7];
    const float* W2   = (const float*)d_in[8];
    const float* b2   = (const float*)d_in[9];
    const float* W3   = (const float*)d_in[10];
    const float* b3   = (const float*)d_in[11];
    const float* Wlin = (const float*)d_in[12];

    char* ws = (char*)d_ws;
    float*          att_logit = (float*)ws;                          // 16384 f32 = 64KB
    unsigned short* wqt = (unsigned short*)(ws + 65536);             // 3*4096 shorts each
    unsigned short* wkt = wqt + 3 * 4096;
    unsigned short* wvt = wkt + 3 * 4096;
    unsigned short* wrt = wvt + 3 * 4096;
    unsigned short* w1p = wrt + 3 * 4096;                            // 2496*512 shorts
    unsigned short* w2p = w1p + 2496 * 512;                          // 256*512 shorts

    attw_t<<<192, 256, 0, stream>>>(WQ, WK, WV, WR, wqt, wkt, wvt, wrt);
    w1pack<<<624, 256, 0, stream>>>(W1, w1p);
    w2pack<<<64, 256, 0, stream>>>(W2, w2p);
    attn_kernel<<<16384, 128, 0, stream>>>(X, emb, wqt, wkt, wvt, wrt, Wlin, att_logit);
    dnn_kernel<<<512, 256, 0, stream>>>(X, emb, w1p, b1, w2p, b2, W3, b3, att_logit,
                                        (float*)d_out);
}